// Round 6
// baseline (204.234 us; speedup 1.0000x reference)
//
#include <hip/hip_runtime.h>
#include <hip/hip_cooperative_groups.h>

namespace cg = cooperative_groups;

#define NN 64
#define N3 (64*64*64)
#define DS 32
#define DS3 (32*32*32)

#define LOG2E 1.4426950408889634f
// sqrt(0.5 * log2(e)) — features pre-scaled so w = exp2(-dot2(d,d))
#define FSCALE 0.8493218002880191f

typedef _Float16 h2  __attribute__((ext_vector_type(2)));
typedef __fp16   h2f __attribute__((ext_vector_type(2)));

__device__ __forceinline__ float fexp2(float x) { return __builtin_amdgcn_exp2f(x); }

__device__ __forceinline__ h2 u2h(unsigned u) { union { unsigned u; h2 h; } c; c.u = u; return c.h; }
__device__ __forceinline__ unsigned h2u(h2 h) { union { unsigned u; h2 h; } c; c.h = h; return c.u; }
__device__ __forceinline__ h2 pkh(float a, float b) {
    union { h2f a; h2 b; } c; c.a = __builtin_amdgcn_cvt_pkrtz(a, b); return c.b;
}
__device__ __forceinline__ float fdot2(h2 a, h2 b) {
    union { h2 h; h2f f; } ca, cb; ca.h = a; cb.h = b;
    return __builtin_amdgcn_fdot2(ca.f, cb.f, 0.0f, false);
}

__device__ __forceinline__ void axw(int j, float scale, int nmax, int& i0, int& i1, float& w) {
    float pos = (float)j * scale;
    int f = (int)floorf(pos);
    if (f < 0) f = 0;
    if (f > nmax) f = nmax;
    i0 = f;
    i1 = (f + 1 <= nmax) ? f + 1 : nmax;
    w = pos - (float)f;
}

// ---------------- prior path ----------------

// outputs: f1pk[DS3] = packed f16x2 of f1*pn*FSCALE
//          nb[DS3]   = { f2 packed, label01 packed, label23 packed, 0 }
__global__ __launch_bounds__(128) void k_downsample(
    const float* __restrict__ img, const float* __restrict__ atlas,
    const float* __restrict__ alabel, const float* __restrict__ pnorm,
    unsigned* __restrict__ f1pk, uint4* __restrict__ nb)
{
    int idx = blockIdx.x * 128 + threadIdx.x;   // grid covers DS3 exactly
    int z = idx & 31, y = (idx >> 5) & 31, x = idx >> 10;

    const float scale = 63.0f / 31.0f;
    int x0,x1,y0,y1,z0,z1; float wx,wy,wz;
    axw(x, scale, 63, x0, x1, wx);
    axw(y, scale, 63, y0, y1, wy);
    axw(z, scale, 63, z0, z1, wz);

    float w000=(1-wx)*(1-wy)*(1-wz), w001=(1-wx)*(1-wy)*wz;
    float w010=(1-wx)*wy*(1-wz),     w011=(1-wx)*wy*wz;
    float w100=wx*(1-wy)*(1-wz),     w101=wx*(1-wy)*wz;
    float w110=wx*wy*(1-wz),         w111=wx*wy*wz;

    int c000=(x0*NN+y0)*NN+z0, c001=(x0*NN+y0)*NN+z1;
    int c010=(x0*NN+y1)*NN+z0, c011=(x0*NN+y1)*NN+z1;
    int c100=(x1*NN+y0)*NN+z0, c101=(x1*NN+y0)*NN+z1;
    int c110=(x1*NN+y1)*NN+z0, c111=(x1*NN+y1)*NN+z1;

    auto tri = [&](const float* p) -> float {
        return p[c000]*w000 + p[c001]*w001 + p[c010]*w010 + p[c011]*w011
             + p[c100]*w100 + p[c101]*w101 + p[c110]*w110 + p[c111]*w111;
    };
    float pnf = pnorm[0] * FSCALE;
    f1pk[idx] = h2u(pkh(pnf*tri(img), pnf*tri(img + N3)));

    auto tril = [&](int c) -> float {
        return alabel[c000*4+c]*w000 + alabel[c001*4+c]*w001 + alabel[c010*4+c]*w010 + alabel[c011*4+c]*w011
             + alabel[c100*4+c]*w100 + alabel[c101*4+c]*w101 + alabel[c110*4+c]*w110 + alabel[c111*4+c]*w111;
    };
    nb[idx] = make_uint4(h2u(pkh(pnf*tri(atlas), pnf*tri(atlas + N3))),
                         h2u(pkh(tril(0), tril(1))),
                         h2u(pkh(tril(2), tril(3))), 0u);
}

__global__ __launch_bounds__(128) void k_prior_msg(
    const unsigned* __restrict__ f1pk, const uint4* __restrict__ nb,
    float4* __restrict__ pm)
{
    int idx = blockIdx.x * 128 + threadIdx.x;
    int z = idx & 31, y = (idx >> 5) & 31, x = idx >> 10;

    h2 ncf = -u2h(f1pk[idx]);
    float a0=0.f, a1=0.f, a2=0.f, a3=0.f;
    for (int dx = -2; dx <= 2; ++dx) {
        int xx = x + dx; if ((unsigned)xx >= DS) continue;
        for (int dy = -2; dy <= 2; ++dy) {
            int yy = y + dy; if ((unsigned)yy >= DS) continue;
            int base = (xx*DS + yy)*DS;
            #pragma unroll
            for (int dz = -2; dz <= 2; ++dz) {
                int zz = z + dz; if ((unsigned)zz >= DS) continue;
                uint4 v = nb[base + zz];
                h2 d = u2h(v.x) + ncf;
                float t = fdot2(d, d);
                float w = fexp2(-t);
                h2 l01 = u2h(v.y), l23 = u2h(v.z);
                a0 += w*(float)l01.x; a1 += w*(float)l01.y;
                a2 += w*(float)l23.x; a3 += w*(float)l23.y;
            }
        }
    }
    pm[idx] = make_float4(a0, a1, a2, a3);
}

// ---------------- cooperative 4-iteration mean-field kernel ----------------
// tile 8x8x16 per block, 1024 threads (tx8, ty8, tzg8, RZ=2, s-split 2 over
// the 25 (dx,dy) phases). grid = 256 blocks = 1 block/CU, 16 waves/CU.
// fS (img features) persistent in LDS across all 4 iterations; prior term
// computed once into registers; cg::grid sync between iterations.

#define TXD 8
#define TYD 8
#define TZR 8
#define RZ 2
#define TZD (TZR*RZ)   // 16
#define HX 12
#define HY 12
#define HZ 20          // z halo extent loaded
#define PZ 22          // padded z stride (even -> 16B-aligned pair reads)

__global__ __launch_bounds__(1024) void k_coop(
    const float* __restrict__ unary,
    const float* __restrict__ img,
    const float* __restrict__ snorm,
    const float* __restrict__ sweight,
    const float* __restrict__ compat,
    const float4* __restrict__ pm,
    const float* __restrict__ pweight,
    const int* __restrict__ pstart,
    float* __restrict__ qA,
    float* __restrict__ qB,
    float* __restrict__ out)
{
    __shared__ __align__(16) uint2    pS[HX][HY][PZ];  // softmax(q) packed f16x4
    __shared__ __align__(8)  unsigned fS[HX][HY][PZ];  // img*sn*FSCALE packed f16x2
    __shared__ __align__(16) uint2    accS[TXD*TYD*TZR][2];

    cg::grid_group gridg = cg::this_grid();

    const int tzg = threadIdx.x, ty = threadIdx.y;
    const int tx = threadIdx.z & 7, s = threadIdx.z >> 3;   // s is wave-uniform
    const int x0b = blockIdx.z * TXD, y0b = blockIdx.y * TYD, z0b = blockIdx.x * TZD;
    const int tid = threadIdx.x + TZR*threadIdx.y + TZR*TYD*threadIdx.z;
    const float sc = snorm[0] * FSCALE;

    // ---- persistent img-feature halo (loaded once) ----
    #pragma unroll
    for (int rr = 0; rr < 3; ++rr) {
        int i = tid + rr*1024;
        if (i < HX*HY*HZ) {
            int lz = i % HZ; int r = i / HZ;
            int ly = r % HY; int lx = r / HY;
            int gx = x0b + lx - 2, gy = y0b + ly - 2, gz = z0b + lz - 2;
            unsigned fu = 0u;
            if ((unsigned)gx < NN && (unsigned)gy < NN && (unsigned)gz < NN) {
                int g = (gx*NN + gy)*NN + gz;
                fu = h2u(pkh(img[g]*sc, img[g+N3]*sc));
            }
            fS[lx][ly][lz] = fu;
        }
    }

    const int tz0 = tzg * RZ;
    const int gx = x0b + tx, gy = y0b + ty, gz = z0b + tz0;
    const int g = (gx*NN + gy)*NN + gz;
    const int pid = (tx*TYD + ty)*TZR + tzg;

    // ---- prior term, once, into registers (s==1 = epilogue owner) ----
    float4 pr0 = make_float4(0.f,0.f,0.f,0.f), pr1 = make_float4(0.f,0.f,0.f,0.f);
    if (s == 1) {
        const float S13 = 31.0f / 63.0f;
        float posx = (float)gx * S13; int xc0 = (int)posx; float wxf = posx - (float)xc0;
        int xc1 = xc0 < 31 ? xc0+1 : 31;
        float posy = (float)gy * S13; int yc0 = (int)posy; float wyf = posy - (float)yc0;
        int yc1 = yc0 < 31 ? yc0+1 : 31;
        int r00i = (xc0*DS+yc0)*DS, r01i = (xc0*DS+yc1)*DS;
        int r10i = (xc1*DS+yc0)*DS, r11i = (xc1*DS+yc1)*DS;
        auto upz = [&](int gzv) -> float4 {
            float posz = (float)gzv * S13; int zc0 = (int)posz; float wzf = posz - (float)zc0;
            int zc1 = zc0 < 31 ? zc0+1 : 31;
            float4 p000 = pm[r00i+zc0], p001 = pm[r00i+zc1];
            float4 p010 = pm[r01i+zc0], p011 = pm[r01i+zc1];
            float4 p100 = pm[r10i+zc0], p101 = pm[r10i+zc1];
            float4 p110 = pm[r11i+zc0], p111 = pm[r11i+zc1];
            float w000=(1-wxf)*(1-wyf)*(1-wzf), w001=(1-wxf)*(1-wyf)*wzf;
            float w010=(1-wxf)*wyf*(1-wzf),     w011=(1-wxf)*wyf*wzf;
            float w100=wxf*(1-wyf)*(1-wzf),     w101=wxf*(1-wyf)*wzf;
            float w110=wxf*wyf*(1-wzf),         w111=wxf*wyf*wzf;
            float4 r;
            r.x = w000*p000.x + w001*p001.x + w010*p010.x + w011*p011.x + w100*p100.x + w101*p101.x + w110*p110.x + w111*p111.x;
            r.y = w000*p000.y + w001*p001.y + w010*p010.y + w011*p011.y + w100*p100.y + w101*p101.y + w110*p110.y + w111*p111.y;
            r.z = w000*p000.z + w001*p001.z + w010*p010.z + w011*p011.z + w100*p100.z + w101*p101.z + w110*p110.z + w111*p111.z;
            r.w = w000*p000.w + w001*p001.w + w010*p010.w + w011*p011.w + w100*p100.w + w101*p101.w + w110*p110.w + w111*p111.w;
            return r;
        };
        pr0 = upz(gz);
        pr1 = upz(gz+1);
        int ps0 = pstart[0], ps1 = pstart[1], ps2 = pstart[2];
        int pwbase = (ps0+gx)*96*96 + (ps1+gy)*96 + ps2 + gz;
        float pwa = pweight[pwbase], pwb = pweight[pwbase+1];
        pr0.x *= pwa; pr0.y *= pwa; pr0.z *= pwa; pr0.w *= pwa;
        pr1.x *= pwb; pr1.y *= pwb; pr1.z *= pwb; pr1.w *= pwb;
    }

    __syncthreads();

    // negated center features (from LDS so the d=0 term is exactly w=1)
    const h2 ncf0 = -u2h(fS[tx+2][ty+2][tz0+2]);
    const h2 ncf1 = -u2h(fS[tx+2][ty+2][tz0+3]);

    for (int it = 0; it < 4; ++it) {
        const float* qin  = (it == 0) ? unary : ((it == 2) ? qB : qA);
        float*       qout = (it == 0) ? qA : ((it == 1) ? qB : ((it == 2) ? qA : out));
        const bool vec_in  = (it != 0);
        const bool vec_out = (it != 3);

        // ---- halo softmax load into pS ----
        #pragma unroll
        for (int rr = 0; rr < 3; ++rr) {
            int i = tid + rr*1024;
            if (i < HX*HY*HZ) {
                int lz = i % HZ; int r = i / HZ;
                int ly = r % HY; int lx = r / HY;
                int ggx = x0b + lx - 2, ggy = y0b + ly - 2, ggz = z0b + lz - 2;
                uint2 pu = make_uint2(0u, 0u);
                if ((unsigned)ggx < NN && (unsigned)ggy < NN && (unsigned)ggz < NN) {
                    int gg = (ggx*NN + ggy)*NN + ggz;
                    float q0, q1, q2, q3;
                    if (vec_in) {
                        float4 qv = reinterpret_cast<const float4*>(qin)[gg];
                        q0 = qv.x; q1 = qv.y; q2 = qv.z; q3 = qv.w;
                    } else {
                        q0 = qin[gg]; q1 = qin[gg+N3]; q2 = qin[gg+2*N3]; q3 = qin[gg+3*N3];
                    }
                    float m = fmaxf(fmaxf(q0,q1), fmaxf(q2,q3));
                    float e0 = fexp2((q0-m)*LOG2E);
                    float e1 = fexp2((q1-m)*LOG2E);
                    float e2 = fexp2((q2-m)*LOG2E);
                    float e3 = fexp2((q3-m)*LOG2E);
                    float inv = 1.0f/(e0+e1+e2+e3);
                    pu = make_uint2(h2u(pkh(e0*inv, e1*inv)), h2u(pkh(e2*inv, e3*inv)));
                }
                pS[lx][ly][lz] = pu;
            }
        }
        __syncthreads();

        // ---- main loop: f16 packed accumulation ----
        h2 a01_0 = (h2)0, a23_0 = (h2)0, a01_1 = (h2)0, a23_1 = (h2)0;

        for (int p = s; p < 25; p += 2) {
            int dx = p / 5, dy = p - dx*5;
            const uint4* pp = reinterpret_cast<const uint4*>(&pS[tx+dx][ty+dy][tz0]);
            const uint2* fp = reinterpret_cast<const uint2*>(&fS[tx+dx][ty+dy][tz0]);
            uint4 qa = pp[0], qb = pp[1], qc = pp[2];     // 6 voxels of packed p
            uint2 fa = fp[0], fb = fp[1], fc = fp[2];     // 6 voxels of packed f

            unsigned fz[6]  = { fa.x, fa.y, fb.x, fb.y, fc.x, fc.y };
            unsigned p01[6] = { qa.x, qa.z, qb.x, qb.z, qc.x, qc.z };
            unsigned p23[6] = { qa.y, qa.w, qb.y, qb.w, qc.y, qc.w };

            #pragma unroll
            for (int dz = 0; dz < 5; ++dz) {
                {
                    h2 d = u2h(fz[dz]) + ncf0;
                    float w = fexp2(-fdot2(d, d));
                    h2 w2 = pkh(w, w);
                    a01_0 = w2 * u2h(p01[dz]) + a01_0;
                    a23_0 = w2 * u2h(p23[dz]) + a23_0;
                }
                {
                    h2 d = u2h(fz[dz+1]) + ncf1;
                    float w = fexp2(-fdot2(d, d));
                    h2 w2 = pkh(w, w);
                    a01_1 = w2 * u2h(p01[dz+1]) + a01_1;
                    a23_1 = w2 * u2h(p23[dz+1]) + a23_1;
                }
            }
        }

        if (s == 0) {
            accS[pid][0] = make_uint2(h2u(a01_0), h2u(a23_0));
            accS[pid][1] = make_uint2(h2u(a01_1), h2u(a23_1));
        }
        __syncthreads();

        if (s == 1) {
            uint2 o0 = accS[pid][0], o1 = accS[pid][1];
            h2 t01_0 = a01_0 + u2h(o0.x), t23_0 = a23_0 + u2h(o0.y);
            h2 t01_1 = a01_1 + u2h(o1.x), t23_1 = a23_1 + u2h(o1.y);

            float2 un0 = *(const float2*)(unary + 0*N3 + g);
            float2 un1 = *(const float2*)(unary + 1*N3 + g);
            float2 un2 = *(const float2*)(unary + 2*N3 + g);
            float2 un3 = *(const float2*)(unary + 3*N3 + g);
            float sw0 = sweight[0], sw1 = sweight[1], sw2 = sweight[2], sw3 = sweight[3];
            float cw[16];
            #pragma unroll
            for (int k = 0; k < 16; ++k) cw[k] = compat[k];

            float p0, p1, p2, p3;
            float r00, r10, r20, r30, r01, r11, r21, r31;
            p0 = sw0*(float)t01_0.x + pr0.x; p1 = sw1*(float)t01_0.y + pr0.y;
            p2 = sw2*(float)t23_0.x + pr0.z; p3 = sw3*(float)t23_0.y + pr0.w;
            r00 = un0.x + cw[0]*p0  + cw[1]*p1  + cw[2]*p2  + cw[3]*p3;
            r10 = un1.x + cw[4]*p0  + cw[5]*p1  + cw[6]*p2  + cw[7]*p3;
            r20 = un2.x + cw[8]*p0  + cw[9]*p1  + cw[10]*p2 + cw[11]*p3;
            r30 = un3.x + cw[12]*p0 + cw[13]*p1 + cw[14]*p2 + cw[15]*p3;
            p0 = sw0*(float)t01_1.x + pr1.x; p1 = sw1*(float)t01_1.y + pr1.y;
            p2 = sw2*(float)t23_1.x + pr1.z; p3 = sw3*(float)t23_1.y + pr1.w;
            r01 = un0.y + cw[0]*p0  + cw[1]*p1  + cw[2]*p2  + cw[3]*p3;
            r11 = un1.y + cw[4]*p0  + cw[5]*p1  + cw[6]*p2  + cw[7]*p3;
            r21 = un2.y + cw[8]*p0  + cw[9]*p1  + cw[10]*p2 + cw[11]*p3;
            r31 = un3.y + cw[12]*p0 + cw[13]*p1 + cw[14]*p2 + cw[15]*p3;

            if (vec_out) {
                reinterpret_cast<float4*>(qout)[g]   = make_float4(r00, r10, r20, r30);
                reinterpret_cast<float4*>(qout)[g+1] = make_float4(r01, r11, r21, r31);
            } else {
                *(float2*)(qout + 0*N3 + g) = make_float2(r00, r01);
                *(float2*)(qout + 1*N3 + g) = make_float2(r10, r11);
                *(float2*)(qout + 2*N3 + g) = make_float2(r20, r21);
                *(float2*)(qout + 3*N3 + g) = make_float2(r30, r31);
            }
        }

        if (it != 3) gridg.sync();
    }
}

// ---------------- launcher ----------------

extern "C" void kernel_launch(void* const* d_in, const int* in_sizes, int n_in,
                              void* d_out, int out_size, void* d_ws, size_t ws_size,
                              hipStream_t stream)
{
    const float* unary   = (const float*)d_in[0];
    const float* img     = (const float*)d_in[1];
    const float* atlas   = (const float*)d_in[2];
    const float* alabel  = (const float*)d_in[3];
    const int*   pstart  = (const int*)d_in[4];
    const float* snorm   = (const float*)d_in[5];
    const float* sweight = (const float*)d_in[6];
    const float* pnorm   = (const float*)d_in[7];
    const float* pweight = (const float*)d_in[8];
    const float* compat  = (const float*)d_in[9];
    float* out = (float*)d_out;
    float* ws  = (float*)d_ws;

    float*    qA   = ws;                            // float4-interleaved q, 4*N3 floats
    float*    qB   = ws + 4*N3;                     // float4-interleaved q, 4*N3 floats
    unsigned* f1pk = (unsigned*)(ws + 8*N3);        // DS3 uints
    uint4*    nbuf = (uint4*)(f1pk + DS3);          // DS3 uint4
    float4*   pm   = (float4*)(nbuf + DS3);         // DS3 float4

    k_downsample<<<DS3/128, 128, 0, stream>>>(img, atlas, alabel, pnorm, f1pk, nbuf);
    k_prior_msg<<<DS3/128, 128, 0, stream>>>(f1pk, nbuf, pm);

    dim3 grid(NN/TZD, NN/TYD, NN/TXD), block(TZR, TYD, 16);
    void* args[] = {
        (void*)&unary, (void*)&img, (void*)&snorm, (void*)&sweight, (void*)&compat,
        (void*)&pm, (void*)&pweight, (void*)&pstart, (void*)&qA, (void*)&qB, (void*)&out
    };
    hipLaunchCooperativeKernel((const void*)k_coop, grid, block, args, 0, stream);
}

// Round 7
// 90.312 us; speedup vs baseline: 2.2614x; 2.2614x over previous
//
#include <hip/hip_runtime.h>

#define NN 64
#define N3 (64*64*64)
#define DS 32
#define DS3 (32*32*32)

#define LOG2E 1.4426950408889634f
// sqrt(0.5 * log2(e)) — features pre-scaled so w = exp2(-dot2(d,d))
#define FSCALE 0.8493218002880191f

typedef _Float16 h2  __attribute__((ext_vector_type(2)));
typedef __fp16   h2f __attribute__((ext_vector_type(2)));

__device__ __forceinline__ float fexp2(float x) { return __builtin_amdgcn_exp2f(x); }

__device__ __forceinline__ h2 u2h(unsigned u) { union { unsigned u; h2 h; } c; c.u = u; return c.h; }
__device__ __forceinline__ unsigned h2u(h2 h) { union { unsigned u; h2 h; } c; c.h = h; return c.u; }
__device__ __forceinline__ h2 pkh(float a, float b) {
    union { h2f a; h2 b; } c; c.a = __builtin_amdgcn_cvt_pkrtz(a, b); return c.b;
}
__device__ __forceinline__ float fdot2(h2 a, h2 b) {
    union { h2 h; h2f f; } ca, cb; ca.h = a; cb.h = b;
    return __builtin_amdgcn_fdot2(ca.f, cb.f, 0.0f, false);
}

__device__ __forceinline__ void axw(int j, float scale, int nmax, int& i0, int& i1, float& w) {
    float pos = (float)j * scale;
    int f = (int)floorf(pos);
    if (f < 0) f = 0;
    if (f > nmax) f = nmax;
    i0 = f;
    i1 = (f + 1 <= nmax) ? f + 1 : nmax;
    w = pos - (float)f;
}

// ---------------- prior path ----------------

__global__ __launch_bounds__(128) void k_downsample(
    const float* __restrict__ img, const float* __restrict__ atlas,
    const float* __restrict__ alabel, const float* __restrict__ pnorm,
    unsigned* __restrict__ f1pk, uint4* __restrict__ nb)
{
    int idx = blockIdx.x * 128 + threadIdx.x;   // grid covers DS3 exactly
    int z = idx & 31, y = (idx >> 5) & 31, x = idx >> 10;

    const float scale = 63.0f / 31.0f;
    int x0,x1,y0,y1,z0,z1; float wx,wy,wz;
    axw(x, scale, 63, x0, x1, wx);
    axw(y, scale, 63, y0, y1, wy);
    axw(z, scale, 63, z0, z1, wz);

    float w000=(1-wx)*(1-wy)*(1-wz), w001=(1-wx)*(1-wy)*wz;
    float w010=(1-wx)*wy*(1-wz),     w011=(1-wx)*wy*wz;
    float w100=wx*(1-wy)*(1-wz),     w101=wx*(1-wy)*wz;
    float w110=wx*wy*(1-wz),         w111=wx*wy*wz;

    int c000=(x0*NN+y0)*NN+z0, c001=(x0*NN+y0)*NN+z1;
    int c010=(x0*NN+y1)*NN+z0, c011=(x0*NN+y1)*NN+z1;
    int c100=(x1*NN+y0)*NN+z0, c101=(x1*NN+y0)*NN+z1;
    int c110=(x1*NN+y1)*NN+z0, c111=(x1*NN+y1)*NN+z1;

    auto tri = [&](const float* p) -> float {
        return p[c000]*w000 + p[c001]*w001 + p[c010]*w010 + p[c011]*w011
             + p[c100]*w100 + p[c101]*w101 + p[c110]*w110 + p[c111]*w111;
    };
    float pnf = pnorm[0] * FSCALE;
    f1pk[idx] = h2u(pkh(pnf*tri(img), pnf*tri(img + N3)));

    auto tril = [&](int c) -> float {
        return alabel[c000*4+c]*w000 + alabel[c001*4+c]*w001 + alabel[c010*4+c]*w010 + alabel[c011*4+c]*w011
             + alabel[c100*4+c]*w100 + alabel[c101*4+c]*w101 + alabel[c110*4+c]*w110 + alabel[c111*4+c]*w111;
    };
    nb[idx] = make_uint4(h2u(pkh(pnf*tri(atlas), pnf*tri(atlas + N3))),
                         h2u(pkh(tril(0), tril(1))),
                         h2u(pkh(tril(2), tril(3))), 0u);
}

__global__ __launch_bounds__(128) void k_prior_msg(
    const unsigned* __restrict__ f1pk, const uint4* __restrict__ nb,
    float4* __restrict__ pm)
{
    int idx = blockIdx.x * 128 + threadIdx.x;
    int z = idx & 31, y = (idx >> 5) & 31, x = idx >> 10;

    h2 ncf = -u2h(f1pk[idx]);
    float a0=0.f, a1=0.f, a2=0.f, a3=0.f;
    for (int dx = -2; dx <= 2; ++dx) {
        int xx = x + dx; if ((unsigned)xx >= DS) continue;
        for (int dy = -2; dy <= 2; ++dy) {
            int yy = y + dy; if ((unsigned)yy >= DS) continue;
            int base = (xx*DS + yy)*DS;
            #pragma unroll
            for (int dz = -2; dz <= 2; ++dz) {
                int zz = z + dz; if ((unsigned)zz >= DS) continue;
                uint4 v = nb[base + zz];
                h2 d = u2h(v.x) + ncf;
                float t = fdot2(d, d);
                float w = fexp2(-t);
                h2 l01 = u2h(v.y), l23 = u2h(v.z);
                a0 += w*(float)l01.x; a1 += w*(float)l01.y;
                a2 += w*(float)l23.x; a3 += w*(float)l23.y;
            }
        }
    }
    pm[idx] = make_float4(a0, a1, a2, a3);
}

// ---------------- mean-field iteration ----------------
// tile 8x8x8 per block, 1024 threads: (tzg=4, ty=8, tx*s=32). Each voxel pair
// (RZ=2 along z) is handled by FOUR waves s=0..3 (wave-uniform split of the 25
// (dx,dy) phases). 512 blocks x 16 waves = 8192 waves = 32 waves/CU = 8/SIMD
// (2 blocks/CU; 35.6 KB LDS each). s==0 owns prior+epilogue (6 phases).

#define TXD 8
#define TYD 8
#define TZD 8
#define TZR 4
#define RZ 2
#define HX 12
#define HY 12
#define HZ 12
#define PZ 14          // padded z stride

template<bool QV_IN, bool QV_OUT>
__global__ __launch_bounds__(1024, 8) void k_iter(
    const float* __restrict__ qin,      // QV_IN ? float4-interleaved : planar [4][N3]
    const float* __restrict__ unary,
    const float* __restrict__ img,
    const float* __restrict__ snorm,
    const float* __restrict__ sweight,
    const float* __restrict__ compat,
    const float4* __restrict__ pm,      // 32^3 prior message
    const float* __restrict__ pweight,
    const int* __restrict__ pstart,
    float* __restrict__ qout)           // QV_OUT ? float4-interleaved : planar
{
    __shared__ __align__(16) uint2    pS[HX][HY][PZ];       // softmax(q) f16x4
    __shared__ __align__(8)  unsigned fS[HX][HY][PZ];       // img*sn*FSCALE f16x2
    __shared__ __align__(16) uint4    accS[3][TXD*TYD*TZR]; // partial sums (16B stride: conflict-free)

    const int tzg = threadIdx.x, ty = threadIdx.y;
    const int tx = threadIdx.z & 7, s = threadIdx.z >> 3;   // s wave-uniform
    const int x0b = blockIdx.z * TXD, y0b = blockIdx.y * TYD, z0b = blockIdx.x * TZD;
    const int tid = threadIdx.x + TZR*threadIdx.y + (TZR*TYD)*threadIdx.z;
    const float sc = snorm[0] * FSCALE;

    // ---- halo load: 12^3 = 1728 voxels, 2 rounds of 1024 ----
    #pragma unroll
    for (int rr = 0; rr < 2; ++rr) {
        int i = tid + rr*1024;
        if (i < HX*HY*HZ) {
            int lz = i % HZ; int r = i / HZ;
            int ly = r % HY; int lx = r / HY;
            int gx = x0b + lx - 2, gy = y0b + ly - 2, gz = z0b + lz - 2;
            uint2 pu = make_uint2(0u, 0u);
            unsigned fu = 0u;
            if ((unsigned)gx < NN && (unsigned)gy < NN && (unsigned)gz < NN) {
                int g = (gx*NN + gy)*NN + gz;
                float q0, q1, q2, q3;
                if (QV_IN) {
                    float4 qv = reinterpret_cast<const float4*>(qin)[g];
                    q0 = qv.x; q1 = qv.y; q2 = qv.z; q3 = qv.w;
                } else {
                    q0 = qin[g]; q1 = qin[g+N3]; q2 = qin[g+2*N3]; q3 = qin[g+3*N3];
                }
                float m = fmaxf(fmaxf(q0,q1), fmaxf(q2,q3));
                float e0 = fexp2((q0-m)*LOG2E);
                float e1 = fexp2((q1-m)*LOG2E);
                float e2 = fexp2((q2-m)*LOG2E);
                float e3 = fexp2((q3-m)*LOG2E);
                float inv = 1.0f/(e0+e1+e2+e3);
                pu = make_uint2(h2u(pkh(e0*inv, e1*inv)), h2u(pkh(e2*inv, e3*inv)));
                fu = h2u(pkh(img[g]*sc, img[g+N3]*sc));
            }
            pS[lx][ly][lz] = pu;
            fS[lx][ly][lz] = fu;
        }
    }
    __syncthreads();

    const int tz0 = tzg * RZ;
    const int gx = x0b + tx, gy = y0b + ty, gz = z0b + tz0;

    // negated center features (from LDS so the d=0 term is exactly w=1)
    const h2 ncf0 = -u2h(fS[tx+2][ty+2][tz0+2]);
    const h2 ncf1 = -u2h(fS[tx+2][ty+2][tz0+3]);

    h2 a01_0 = (h2)0, a23_0 = (h2)0, a01_1 = (h2)0, a23_1 = (h2)0;

    // wave-uniform split of the 25 (dx,dy) phases across s=0..3; s==3 gets 7,
    // s==0 (epilogue owner) gets 6.
    #pragma unroll
    for (int pp = 0; pp < 7; ++pp) {
        int p = (3 - s) + 4*pp;
        if (p < 25) {
            int dx = p / 5, dy = p - 5*dx;
            const uint4* pv = reinterpret_cast<const uint4*>(&pS[tx+dx][ty+dy][tz0]);
            const uint2* fv = reinterpret_cast<const uint2*>(&fS[tx+dx][ty+dy][tz0]);
            uint4 qa = pv[0], qb = pv[1], qc = pv[2];   // 6 voxels of packed p
            uint2 fa = fv[0], fb = fv[1], fc = fv[2];   // 6 voxels of packed f

            unsigned fz[6]  = { fa.x, fa.y, fb.x, fb.y, fc.x, fc.y };
            unsigned p01[6] = { qa.x, qa.z, qb.x, qb.z, qc.x, qc.z };
            unsigned p23[6] = { qa.y, qa.w, qb.y, qb.w, qc.y, qc.w };

            #pragma unroll
            for (int dz = 0; dz < 5; ++dz) {
                {
                    h2 d = u2h(fz[dz]) + ncf0;
                    float w = fexp2(-fdot2(d, d));
                    h2 w2 = pkh(w, w);
                    a01_0 = w2 * u2h(p01[dz]) + a01_0;
                    a23_0 = w2 * u2h(p23[dz]) + a23_0;
                }
                {
                    h2 d = u2h(fz[dz+1]) + ncf1;
                    float w = fexp2(-fdot2(d, d));
                    h2 w2 = pkh(w, w);
                    a01_1 = w2 * u2h(p01[dz+1]) + a01_1;
                    a23_1 = w2 * u2h(p23[dz+1]) + a23_1;
                }
            }
        }
    }

    const int pid = (tx*TYD + ty)*TZR + tzg;
    if (s != 0) {
        accS[s-1][pid] = make_uint4(h2u(a01_0), h2u(a23_0), h2u(a01_1), h2u(a23_1));
    }

    // ---- prior term: s==0 computes it WHILE s!=0 waves finish their phases ----
    float4 pr0 = make_float4(0.f,0.f,0.f,0.f), pr1 = make_float4(0.f,0.f,0.f,0.f);
    if (s == 0) {
        const float S13 = 31.0f / 63.0f;
        float posx = (float)gx * S13; int xc0 = (int)posx; float wxf = posx - (float)xc0;
        int xc1 = xc0 < 31 ? xc0+1 : 31;
        float posy = (float)gy * S13; int yc0 = (int)posy; float wyf = posy - (float)yc0;
        int yc1 = yc0 < 31 ? yc0+1 : 31;
        int r00i = (xc0*DS+yc0)*DS, r01i = (xc0*DS+yc1)*DS;
        int r10i = (xc1*DS+yc0)*DS, r11i = (xc1*DS+yc1)*DS;
        auto upz = [&](int gzv) -> float4 {
            float posz = (float)gzv * S13; int zc0 = (int)posz; float wzf = posz - (float)zc0;
            int zc1 = zc0 < 31 ? zc0+1 : 31;
            float4 p000 = pm[r00i+zc0], p001 = pm[r00i+zc1];
            float4 p010 = pm[r01i+zc0], p011 = pm[r01i+zc1];
            float4 p100 = pm[r10i+zc0], p101 = pm[r10i+zc1];
            float4 p110 = pm[r11i+zc0], p111 = pm[r11i+zc1];
            float w000=(1-wxf)*(1-wyf)*(1-wzf), w001=(1-wxf)*(1-wyf)*wzf;
            float w010=(1-wxf)*wyf*(1-wzf),     w011=(1-wxf)*wyf*wzf;
            float w100=wxf*(1-wyf)*(1-wzf),     w101=wxf*(1-wyf)*wzf;
            float w110=wxf*wyf*(1-wzf),         w111=wxf*wyf*wzf;
            float4 r;
            r.x = w000*p000.x + w001*p001.x + w010*p010.x + w011*p011.x + w100*p100.x + w101*p101.x + w110*p110.x + w111*p111.x;
            r.y = w000*p000.y + w001*p001.y + w010*p010.y + w011*p011.y + w100*p100.y + w101*p101.y + w110*p110.y + w111*p111.y;
            r.z = w000*p000.z + w001*p001.z + w010*p010.z + w011*p011.z + w100*p100.z + w101*p101.z + w110*p110.z + w111*p111.z;
            r.w = w000*p000.w + w001*p001.w + w010*p010.w + w011*p011.w + w100*p100.w + w101*p101.w + w110*p110.w + w111*p111.w;
            return r;
        };
        pr0 = upz(gz);
        pr1 = upz(gz+1);
        int ps0 = pstart[0], ps1 = pstart[1], ps2 = pstart[2];
        int pwbase = (ps0+gx)*96*96 + (ps1+gy)*96 + ps2 + gz;
        float pwa = pweight[pwbase], pwb = pweight[pwbase+1];
        pr0.x *= pwa; pr0.y *= pwa; pr0.z *= pwa; pr0.w *= pwa;
        pr1.x *= pwb; pr1.y *= pwb; pr1.z *= pwb; pr1.w *= pwb;
    }

    __syncthreads();

    if (s == 0) {
        #pragma unroll
        for (int j = 0; j < 3; ++j) {
            uint4 v = accS[j][pid];
            a01_0 += u2h(v.x); a23_0 += u2h(v.y);
            a01_1 += u2h(v.z); a23_1 += u2h(v.w);
        }

        const int g = (gx*NN + gy)*NN + gz;
        float2 un0 = *(const float2*)(unary + 0*N3 + g);
        float2 un1 = *(const float2*)(unary + 1*N3 + g);
        float2 un2 = *(const float2*)(unary + 2*N3 + g);
        float2 un3 = *(const float2*)(unary + 3*N3 + g);
        float sw0 = sweight[0], sw1 = sweight[1], sw2 = sweight[2], sw3 = sweight[3];
        float cw[16];
        #pragma unroll
        for (int k = 0; k < 16; ++k) cw[k] = compat[k];

        float p0, p1, p2, p3;
        float r00, r10, r20, r30, r01, r11, r21, r31;
        p0 = sw0*(float)a01_0.x + pr0.x; p1 = sw1*(float)a01_0.y + pr0.y;
        p2 = sw2*(float)a23_0.x + pr0.z; p3 = sw3*(float)a23_0.y + pr0.w;
        r00 = un0.x + cw[0]*p0  + cw[1]*p1  + cw[2]*p2  + cw[3]*p3;
        r10 = un1.x + cw[4]*p0  + cw[5]*p1  + cw[6]*p2  + cw[7]*p3;
        r20 = un2.x + cw[8]*p0  + cw[9]*p1  + cw[10]*p2 + cw[11]*p3;
        r30 = un3.x + cw[12]*p0 + cw[13]*p1 + cw[14]*p2 + cw[15]*p3;
        p0 = sw0*(float)a01_1.x + pr1.x; p1 = sw1*(float)a01_1.y + pr1.y;
        p2 = sw2*(float)a23_1.x + pr1.z; p3 = sw3*(float)a23_1.y + pr1.w;
        r01 = un0.y + cw[0]*p0  + cw[1]*p1  + cw[2]*p2  + cw[3]*p3;
        r11 = un1.y + cw[4]*p0  + cw[5]*p1  + cw[6]*p2  + cw[7]*p3;
        r21 = un2.y + cw[8]*p0  + cw[9]*p1  + cw[10]*p2 + cw[11]*p3;
        r31 = un3.y + cw[12]*p0 + cw[13]*p1 + cw[14]*p2 + cw[15]*p3;

        if (QV_OUT) {
            reinterpret_cast<float4*>(qout)[g]   = make_float4(r00, r10, r20, r30);
            reinterpret_cast<float4*>(qout)[g+1] = make_float4(r01, r11, r21, r31);
        } else {
            *(float2*)(qout + 0*N3 + g) = make_float2(r00, r01);
            *(float2*)(qout + 1*N3 + g) = make_float2(r10, r11);
            *(float2*)(qout + 2*N3 + g) = make_float2(r20, r21);
            *(float2*)(qout + 3*N3 + g) = make_float2(r30, r31);
        }
    }
}

// ---------------- launcher ----------------

extern "C" void kernel_launch(void* const* d_in, const int* in_sizes, int n_in,
                              void* d_out, int out_size, void* d_ws, size_t ws_size,
                              hipStream_t stream)
{
    const float* unary   = (const float*)d_in[0];
    const float* img     = (const float*)d_in[1];
    const float* atlas   = (const float*)d_in[2];
    const float* alabel  = (const float*)d_in[3];
    const int*   pstart  = (const int*)d_in[4];
    const float* snorm   = (const float*)d_in[5];
    const float* sweight = (const float*)d_in[6];
    const float* pnorm   = (const float*)d_in[7];
    const float* pweight = (const float*)d_in[8];
    const float* compat  = (const float*)d_in[9];
    float* out = (float*)d_out;
    float* ws  = (float*)d_ws;

    float*    qA   = ws;                            // float4-interleaved q, 4*N3 floats
    float*    qB   = ws + 4*N3;                     // float4-interleaved q, 4*N3 floats
    unsigned* f1pk = (unsigned*)(ws + 8*N3);        // DS3 uints
    uint4*    nbuf = (uint4*)(f1pk + DS3);          // DS3 uint4
    float4*   pm   = (float4*)(nbuf + DS3);         // DS3 float4

    k_downsample<<<DS3/128, 128, 0, stream>>>(img, atlas, alabel, pnorm, f1pk, nbuf);
    k_prior_msg<<<DS3/128, 128, 0, stream>>>(f1pk, nbuf, pm);

    dim3 grid(NN/TZD, NN/TYD, NN/TXD), block(TZR, TYD, 32);
    k_iter<false,true><<<grid, block, 0, stream>>>(unary, unary, img, snorm, sweight, compat, pm, pweight, pstart, qA);
    k_iter<true, true><<<grid, block, 0, stream>>>(qA,    unary, img, snorm, sweight, compat, pm, pweight, pstart, qB);
    k_iter<true, true><<<grid, block, 0, stream>>>(qB,    unary, img, snorm, sweight, compat, pm, pweight, pstart, qA);
    k_iter<true,false><<<grid, block, 0, stream>>>(qA,    unary, img, snorm, sweight, compat, pm, pweight, pstart, out);
}